// Round 12
// baseline (55.111 us; speedup 1.0000x reference)
//
#include <hip/hip_runtime.h>

#define EPSF 1e-5f
#define KSTR 68    // kb K/V LDS row stride (floats)
#define PSTR 260   // kb P row stride (floats)

#define FMA4(ACC, ZS, WV) \
    ACC.x = fmaf(ZS, WV.x, ACC.x); ACC.y = fmaf(ZS, WV.y, ACC.y); \
    ACC.z = fmaf(ZS, WV.z, ACC.z); ACC.w = fmaf(ZS, WV.w, ACC.w);

// ---------------------------------------------------------------------------
// GEMM pass, 8-token/thread form [R6-verified, unchanged]
// ---------------------------------------------------------------------------
__device__ __forceinline__ void pass8x8(
    const float* __restrict__ W, const float* __restrict__ zr,
    float* __restrict__ ps, int kq, int ln)
{
    const float* wr = W + kq * 8192 + 4 * ln;    // k-row base
    const float* zb = zr + kq * 32;
    float4 a0 = make_float4(0.f,0.f,0.f,0.f), a1 = a0, a2 = a0, a3 = a0;
    float4 a4 = a0, a5 = a0, a6 = a0, a7 = a0;
    #pragma unroll
    for (int kk = 0; kk < 32; kk += 4) {
        float4 w0 = *(const float4*)(wr + (kk + 0) * 256);
        float4 w1 = *(const float4*)(wr + (kk + 1) * 256);
        float4 w2 = *(const float4*)(wr + (kk + 2) * 256);
        float4 w3 = *(const float4*)(wr + (kk + 3) * 256);
        float4 z0 = *(const float4*)(zb + 0 * 256 + kk);
        float4 z1 = *(const float4*)(zb + 1 * 256 + kk);
        float4 z2 = *(const float4*)(zb + 2 * 256 + kk);
        float4 z3 = *(const float4*)(zb + 3 * 256 + kk);
        float4 z4 = *(const float4*)(zb + 4 * 256 + kk);
        float4 z5 = *(const float4*)(zb + 5 * 256 + kk);
        float4 z6 = *(const float4*)(zb + 6 * 256 + kk);
        float4 z7 = *(const float4*)(zb + 7 * 256 + kk);
        FMA4(a0, z0.x, w0) FMA4(a0, z0.y, w1) FMA4(a0, z0.z, w2) FMA4(a0, z0.w, w3)
        FMA4(a1, z1.x, w0) FMA4(a1, z1.y, w1) FMA4(a1, z1.z, w2) FMA4(a1, z1.w, w3)
        FMA4(a2, z2.x, w0) FMA4(a2, z2.y, w1) FMA4(a2, z2.z, w2) FMA4(a2, z2.w, w3)
        FMA4(a3, z3.x, w0) FMA4(a3, z3.y, w1) FMA4(a3, z3.z, w2) FMA4(a3, z3.w, w3)
        FMA4(a4, z4.x, w0) FMA4(a4, z4.y, w1) FMA4(a4, z4.z, w2) FMA4(a4, z4.w, w3)
        FMA4(a5, z5.x, w0) FMA4(a5, z5.y, w1) FMA4(a5, z5.z, w2) FMA4(a5, z5.w, w3)
        FMA4(a6, z6.x, w0) FMA4(a6, z6.y, w1) FMA4(a6, z6.z, w2) FMA4(a6, z6.w, w3)
        FMA4(a7, z7.x, w0) FMA4(a7, z7.y, w1) FMA4(a7, z7.z, w2) FMA4(a7, z7.w, w3)
    }
    float* pp = ps + kq * 2048 + 4 * ln;
    *(float4*)(pp + 0 * 256) = a0;
    *(float4*)(pp + 1 * 256) = a1;
    *(float4*)(pp + 2 * 256) = a2;
    *(float4*)(pp + 3 * 256) = a3;
    *(float4*)(pp + 4 * 256) = a4;
    *(float4*)(pp + 5 * 256) = a5;
    *(float4*)(pp + 6 * 256) = a6;
    *(float4*)(pp + 7 * 256) = a7;
}

__device__ __forceinline__ float4 combine8(const float* __restrict__ ps, int e)
{
    float4 a = *(const float4*)(ps + e);
    #pragma unroll
    for (int k = 1; k < 8; ++k) {
        float4 u = *(const float4*)(ps + k * 2048 + e);
        a.x += u.x; a.y += u.y; a.z += u.z; a.w += u.w;
    }
    return a;
}

// ---------------------------------------------------------------------------
// KA v3: patch embed + LN + NF + QKV. [R8/R11 form, verified best]
// ---------------------------------------------------------------------------
__global__ __launch_bounds__(512, 2) void ka_patch_nf_qkv(
    const float* __restrict__ x,
    const float* __restrict__ Wp, const float* __restrict__ bp,
    const float* __restrict__ ln_g, const float* __restrict__ ln_b,
    const float* __restrict__ Wq, const float* __restrict__ bq,
    const float* __restrict__ Wk, const float* __restrict__ bk,
    const float* __restrict__ Wv, const float* __restrict__ bv,
    float* __restrict__ Qg, float* __restrict__ Kg, float* __restrict__ Vg)
{
    extern __shared__ float sm[];
    float* zr  = sm;           // [8][256] patch rows, then z rows
    float* psA = sm + 2048;    // [8][8][256] (64 KB)
    float* psB = sm + 18432;   // [8][8][256] (64 KB)

    const int tid = threadIdx.x;
    const int kq = tid >> 6, ln = tid & 63;
    const int lane = tid & 63;
    const int tok0 = blockIdx.x * 8;

    // ---- stage 8 patches as rows (float4/thread) ----
    {
        int e = tid * 4;
        int t = e >> 8, dd = e & 255;
        int tk = tok0 + t, b = tk >> 8, n = tk & 255;
        int ph = n >> 4, pw = n & 15, p = (dd >> 4) & 15, q = dd & 15;
        *(float4*)(zr + e) =
            *(const float4*)(x + b * 65536 + (ph * 16 + p) * 256 + pw * 16 + q);
    }
    __syncthreads();

    // ---- pass 0: z = patch @ Wp -> psA ----
    pass8x8(Wp, zr, psA, kq, ln);
    __syncthreads();

    // ---- combine + bias + in-register LN/NF (token = wave) ----
    {
        int e = tid * 4;                       // token tid>>6, dims 4*lane..+4
        float4 a = combine8(psA, e);
        float4 bb = *(const float4*)(bp + 4 * lane);
        a.x += bb.x; a.y += bb.y; a.z += bb.z; a.w += bb.w;

        float s  = a.x + a.y + a.z + a.w;
        float ss = a.x*a.x + a.y*a.y + a.z*a.z + a.w*a.w;
        #pragma unroll
        for (int o = 32; o; o >>= 1) { s += __shfl_xor(s, o); ss += __shfl_xor(ss, o); }
        float mu  = s * (1.f / 256.f);
        float var = ss * (1.f / 256.f) - mu * mu;
        float rs  = rsqrtf(var + EPSF);

        float4 g  = *(const float4*)(ln_g + 4 * lane);
        float4 b2 = *(const float4*)(ln_b + 4 * lane);
        float4 zn;
        zn.x = (a.x - mu) * rs * g.x + b2.x;
        zn.y = (a.y - mu) * rs * g.y + b2.y;
        zn.z = (a.z - mu) * rs * g.z + b2.z;
        zn.w = (a.w - mu) * rs * g.w + b2.w;

        float s2  = zn.x + zn.y + zn.z + zn.w;
        float ss2 = zn.x*zn.x + zn.y*zn.y + zn.z*zn.z + zn.w*zn.w;
        #pragma unroll
        for (int o = 32; o; o >>= 1) { s2 += __shfl_xor(s2, o); ss2 += __shfl_xor(ss2, o); }
        float mu2  = s2 * (1.f / 256.f);
        float var2 = ss2 * (1.f / 256.f) - mu2 * mu2;

        float as = fabsf(zn.x - mu2) + fabsf(zn.y - mu2)
                 + fabsf(zn.z - mu2) + fabsf(zn.w - mu2);
        #pragma unroll
        for (int o = 32; o; o >>= 1) as += __shfl_xor(as, o);
        float nf = as / (sqrtf(var2 + EPSF) + EPSF);
        float sc = 1.f + nf;
        zn.x *= sc; zn.y *= sc; zn.z *= sc; zn.w *= sc;
        *(float4*)(zr + e) = zn;
    }
    __syncthreads();

    // ---- QKV: double-buffered pass/combine pipeline ----
    int e = tid * 4, t = e >> 8, d0 = e & 255;
    int tk = tok0 + t, b = tk >> 8, n = tk & 255;
    int h = d0 >> 6, dh = d0 & 63;
    const long goff = ((long)(b * 4 + h) * 256 + n) * 64 + dh;

    pass8x8(Wq, zr, psB, kq, ln);
    __syncthreads();

    // phase: combine Q (psB) + pass K (psA)
    {
        float4 a = combine8(psB, e);
        float4 bb = *(const float4*)(bq + d0);
        a.x += bb.x; a.y += bb.y; a.z += bb.z; a.w += bb.w;
        *(float4*)(Qg + goff) = a;
    }
    pass8x8(Wk, zr, psA, kq, ln);
    __syncthreads();

    // phase: combine K (psA) + pass V (psB)
    {
        float4 a = combine8(psA, e);
        float4 bb = *(const float4*)(bk + d0);
        a.x += bb.x; a.y += bb.y; a.z += bb.z; a.w += bb.w;
        *(float4*)(Kg + goff) = a;
    }
    pass8x8(Wv, zr, psB, kq, ln);
    __syncthreads();

    // final: combine V (psB)
    {
        float4 a = combine8(psB, e);
        float4 bb = *(const float4*)(bv + d0);
        a.x += bb.x; a.y += bb.y; a.z += bb.z; a.w += bb.w;
        *(float4*)(Vg + goff) = a;
    }
}

// ---------------------------------------------------------------------------
// KB v6: AG-NFA attention at 1024 threads (16 waves/CU = 4 waves/SIMD,
// double the TLP of v4; same 140 KB LDS -> still 1 block/CU).
// Thread = (q=tid>>5 in [0,32), rlo=(tid&31)&15, rhi=(tid&31)>>4).
//  - QK^T: dot split into two 32-dim c-halves across rhi, combined via
//    shfl_xor(.,16). K reads stay 16-distinct-row (conflict-free),
//    128 f4/thread.
//  - PV: m-range split across rhi (128 m/thread), 4-shuffle combine.
//  - Staging/k2 remapped to 1024 threads. Math = v4 up to reassociation.
// ---------------------------------------------------------------------------
__global__ __launch_bounds__(1024, 4) void kb_attn(
    const float* __restrict__ Qg, const float* __restrict__ Kg,
    const float* __restrict__ Vg, float* __restrict__ Og)
{
    extern __shared__ float lds[];
    float* Kl = lds;                   // [256][KSTR]
    float* Vl = lds + 256 * KSTR;      // [256][KSTR]
    float* k2 = lds + 2 * 256 * KSTR;  // [256]
    float* Pl = Kl;                    // [32][PSTR] overlay on Kl after QK^T

    const int tid = threadIdx.x;
    const int xcd = blockIdx.x & 7, slot = blockIdx.x >> 3;
    const int bh = xcd * 4 + (slot >> 3);
    const int qt = slot & 7;

    const float* Qb = Qg + (bh * 256 + qt * 32) * 64;
    const float* Kb = Kg + bh * 16384;
    const float* Vb = Vg + bh * 16384;

    const int q   = tid >> 5;          // 0..31: query row
    const int r   = tid & 31;
    const int rlo = r & 15;
    const int rhi = r >> 4;            // 0/1: c-half (QK^T) / m-half (PV)

    // ---- stage K and V -> LDS (fully coalesced; 4 f4 each) ----
    {
        const float4* Ks = (const float4*)Kb;
        const float4* Vs = (const float4*)Vb;
        #pragma unroll
        for (int i = 0; i < 4; ++i) {
            int flat = tid + 1024 * i;           // f4 index, 4096 total
            int row = flat >> 4, c4 = flat & 15;
            *(float4*)(Kl + row * KSTR + c4 * 4) = Ks[flat];
            *(float4*)(Vl + row * KSTR + c4 * 4) = Vs[flat];
        }
    }
    __syncthreads();

    // ---- k2[m] = |K_m|^2 : 4 threads per row ----
    {
        int row = tid >> 2, part = tid & 3;
        const float* kp = Kl + row * KSTR + part * 16;
        float ssq = 0.f;
        #pragma unroll
        for (int c = 0; c < 4; ++c) {
            float4 kv = *(const float4*)(kp + 4 * c);
            ssq += kv.x*kv.x + kv.y*kv.y + kv.z*kv.z + kv.w*kv.w;
        }
        ssq += __shfl_xor(ssq, 1);
        ssq += __shfl_xor(ssq, 2);
        if (part == 0) k2[row] = ssq;
    }

    // ---- NF stats: full Q row pass (thread-local, values discarded) ----
    float fq, gq, iq;
    {
        const float4* Qp = (const float4*)(Qb + q * 64);
        float s = 0.f, ss = 0.f;
        float4 vbuf[16];
        #pragma unroll
        for (int c = 0; c < 16; ++c) {
            float4 v = Qp[c];
            vbuf[c] = v;
            s  += v.x + v.y + v.z + v.w;
            ss += v.x*v.x + v.y*v.y + v.z*v.z + v.w*v.w;
        }
        float mu = s * (1.f / 64.f);
        float as = 0.f;
        #pragma unroll
        for (int c = 0; c < 16; ++c) {
            float4 v = vbuf[c];
            as += fabsf(v.x - mu) + fabsf(v.y - mu)
                + fabsf(v.z - mu) + fabsf(v.w - mu);
        }
        float var = ss * (1.f / 64.f) - mu * mu;
        float sg  = sqrtf(var + EPSF);
        float nf  = as / (sg + EPSF);
        float inv = 1.f / (__expf(-nf) + 1.f);
        fq = 0.125f + 2.f * inv;
        gq = ss * inv;
        iq = inv;
    }

    // ---- Q c-half for QK^T (8 f4, L1-hot reload) ----
    float4 Qh[8];
    {
        const float4* Qp = (const float4*)(Qb + q * 64) + rhi * 8;
        #pragma unroll
        for (int c = 0; c < 8; ++c) Qh[c] = Qp[c];
    }
    __syncthreads();   // k2 visible

    // ---- QK^T: m = rlo + 16j; partial dot over own c-half, xor-combine ----
    float s_[16];
    #pragma unroll
    for (int j = 0; j < 16; ++j) {
        int m = rlo + 16 * j;
        const float* kp = Kl + m * KSTR + rhi * 32;
        float acc = 0.f;
        #pragma unroll
        for (int c = 0; c < 8; ++c) {
            float4 kv = *(const float4*)(kp + 4 * c);
            acc += Qh[c].x*kv.x + Qh[c].y*kv.y + Qh[c].z*kv.z + Qh[c].w*kv.w;
        }
        acc += __shfl_xor(acc, 16);    // combine c-halves (both rhi get full)
        s_[j] = acc * fq - gq - k2[m] * iq;
    }

    // ---- softmax over m (reduce across 16 rlo lanes; rhi duplicated) ----
    float M = s_[0];
    #pragma unroll
    for (int j = 1; j < 16; ++j) M = fmaxf(M, s_[j]);
    #pragma unroll
    for (int o = 1; o < 16; o <<= 1) M = fmaxf(M, __shfl_xor(M, o));
    float L = 0.f;
    #pragma unroll
    for (int j = 0; j < 16; ++j) { s_[j] = __expf(s_[j] - M); L += s_[j]; }
    #pragma unroll
    for (int o = 1; o < 16; o <<= 1) L += __shfl_xor(L, o);
    float invL = 1.f / L;

    __syncthreads();   // done reading Kl/k2 -> overlay Pl (Vl untouched)
    if (rhi == 0) {
        #pragma unroll
        for (int j = 0; j < 16; ++j) Pl[q * PSTR + rlo + 16 * j] = s_[j] * invL;
    }
    __syncthreads();

    // ---- PV: thread owns d = 4*rlo..+4 over m-half rhi; xor-combine ----
    float4 a0 = make_float4(0.f, 0.f, 0.f, 0.f);
    const float* pq = Pl + q * PSTR + rhi * 128;
    const float* vp = Vl + rhi * 128 * KSTR + 4 * rlo;
    #pragma unroll 8
    for (int m = 0; m < 128; ++m) {
        float pw = pq[m];
        float4 v = *(const float4*)(vp + m * KSTR);
        a0.x = fmaf(pw, v.x, a0.x); a0.y = fmaf(pw, v.y, a0.y);
        a0.z = fmaf(pw, v.z, a0.z); a0.w = fmaf(pw, v.w, a0.w);
    }
    a0.x += __shfl_xor(a0.x, 16);
    a0.y += __shfl_xor(a0.y, 16);
    a0.z += __shfl_xor(a0.z, 16);
    a0.w += __shfl_xor(a0.w, 16);
    if (rhi == 0) {
        int b = bh >> 2, h = bh & 3;
        int n = qt * 32 + q;
        float* op = Og + (b * 256 + n) * 256 + h * 64 + 4 * rlo;
        *(float4*)op = a0;
    }
}

// ---------------------------------------------------------------------------
// KC v2: Y = attn_out @ Wo + bo, then LE-fusion. [R8/R11 form, verified]
// ---------------------------------------------------------------------------
__global__ __launch_bounds__(512, 2) void kc_wo_le(
    const float* __restrict__ Og, const float* __restrict__ Wo,
    const float* __restrict__ bo, float* __restrict__ out)
{
    extern __shared__ float sm[];
    float* yr  = sm;           // [8][256]
    float* ps  = sm + 2048;    // [8][8][256] (64 KB)
    float* red = sm + 18432;   // [8]

    const int tid = threadIdx.x;
    const int kq = tid >> 6, ln = tid & 63;
    const int wave = tid >> 6, lane = tid & 63;
    const int tok0 = blockIdx.x * 8;

    *(float4*)(yr + tid * 4) = *(const float4*)(Og + tok0 * 256 + tid * 4);
    __syncthreads();

    pass8x8(Wo, yr, ps, kq, ln);
    __syncthreads();

    // combine + bias + in-register ||Y|| (token = wave), write yr row
    {
        int e = tid * 4;
        float4 a = combine8(ps, e);
        float4 bb = *(const float4*)(bo + 4 * lane);
        a.x += bb.x; a.y += bb.y; a.z += bb.z; a.w += bb.w;
        float ssq = a.x*a.x + a.y*a.y + a.z*a.z + a.w*a.w;
        #pragma unroll
        for (int o = 32; o; o >>= 1) ssq += __shfl_xor(ssq, o);
        if (lane == 0) red[wave] = sqrtf(ssq);
        *(float4*)(yr + e) = a;
    }
    __syncthreads();

    // LE-fusion
    {
        int g = tid >> 8, d = tid & 255;
        float e0 = red[4 * g], e1 = red[4 * g + 1], e2 = red[4 * g + 2], e3 = red[4 * g + 3];
        float m = fmaxf(fmaxf(e0, e1), fmaxf(e2, e3));
        float x0 = __expf(e0 - m), x1 = __expf(e1 - m), x2 = __expf(e2 - m), x3 = __expf(e3 - m);
        float inv = 1.f / (x0 + x1 + x2 + x3);
        float val = (x0 * yr[(4 * g) * 256 + d] + x1 * yr[(4 * g + 1) * 256 + d]
                   + x2 * yr[(4 * g + 2) * 256 + d] + x3 * yr[(4 * g + 3) * 256 + d]) * inv;
        out[(blockIdx.x * 2 + g) * 256 + d] = val;
    }
}

// ---------------------------------------------------------------------------
extern "C" void kernel_launch(void* const* d_in, const int* in_sizes, int n_in,
                              void* d_out, int out_size, void* d_ws, size_t ws_size,
                              hipStream_t stream) {
    const float* x    = (const float*)d_in[0];
    const float* Wp   = (const float*)d_in[1];
    const float* bp   = (const float*)d_in[2];
    const float* ln_g = (const float*)d_in[3];
    const float* ln_b = (const float*)d_in[4];
    const float* Wq   = (const float*)d_in[5];
    const float* bq   = (const float*)d_in[6];
    const float* Wk   = (const float*)d_in[7];
    const float* bk   = (const float*)d_in[8];
    const float* Wv   = (const float*)d_in[9];
    const float* bv   = (const float*)d_in[10];
    const float* Wo   = (const float*)d_in[11];
    const float* bo   = (const float*)d_in[12];
    float* out = (float*)d_out;

    float* ws = (float*)d_ws;
    float* Qg = ws;
    float* Kg = ws + 524288;
    float* Vg = ws + 524288 * 2;
    float* Og = ws + 524288 * 3;

    const int ka_lds = (2048 + 2 * 16384) * 4;          // 139264 B
    const int kb_lds = (2 * 256 * KSTR + 256) * 4;      // 140288 B
    const int kc_lds = (2048 + 16384 + 8) * 4;          // 73760 B
    (void)hipFuncSetAttribute((const void*)ka_patch_nf_qkv,
                              hipFuncAttributeMaxDynamicSharedMemorySize, ka_lds);
    (void)hipFuncSetAttribute((const void*)kb_attn,
                              hipFuncAttributeMaxDynamicSharedMemorySize, kb_lds);
    (void)hipFuncSetAttribute((const void*)kc_wo_le,
                              hipFuncAttributeMaxDynamicSharedMemorySize, kc_lds);

    ka_patch_nf_qkv<<<256, 512, ka_lds, stream>>>(x, Wp, bp, ln_g, ln_b,
                                                  Wq, bq, Wk, bk, Wv, bv, Qg, Kg, Vg);
    kb_attn<<<256, 1024, kb_lds, stream>>>(Qg, Kg, Vg, Og);
    kc_wo_le<<<256, 512, kc_lds, stream>>>(Og, Wo, bo, out);
}

// Round 13
// 49.423 us; speedup vs baseline: 1.1151x; 1.1151x over previous
//
#include <hip/hip_runtime.h>

#define EPSF 1e-5f
#define KSTR 68    // kb K/V LDS row stride (floats)
#define PSTR 260   // kb P row stride (floats)

#define FMA4(ACC, ZS, WV) \
    ACC.x = fmaf(ZS, WV.x, ACC.x); ACC.y = fmaf(ZS, WV.y, ACC.y); \
    ACC.z = fmaf(ZS, WV.z, ACC.z); ACC.w = fmaf(ZS, WV.w, ACC.w);

// ---------------------------------------------------------------------------
// GEMM pass, 8-token/thread form: thread (kq=tid>>6 in [0,8), ln=tid&63)
// owns k-rows [32kq,32kq+32), ALL 8 tokens, dims [4ln,4ln+4).
// VMEM:VALU instruction ratio 1:32. Partials ps[kq][tok][256] (64 KB).
// [R6-verified]
// ---------------------------------------------------------------------------
__device__ __forceinline__ void pass8x8(
    const float* __restrict__ W, const float* __restrict__ zr,
    float* __restrict__ ps, int kq, int ln)
{
    const float* wr = W + kq * 8192 + 4 * ln;    // k-row base
    const float* zb = zr + kq * 32;
    float4 a0 = make_float4(0.f,0.f,0.f,0.f), a1 = a0, a2 = a0, a3 = a0;
    float4 a4 = a0, a5 = a0, a6 = a0, a7 = a0;
    #pragma unroll
    for (int kk = 0; kk < 32; kk += 4) {
        float4 w0 = *(const float4*)(wr + (kk + 0) * 256);
        float4 w1 = *(const float4*)(wr + (kk + 1) * 256);
        float4 w2 = *(const float4*)(wr + (kk + 2) * 256);
        float4 w3 = *(const float4*)(wr + (kk + 3) * 256);
        float4 z0 = *(const float4*)(zb + 0 * 256 + kk);
        float4 z1 = *(const float4*)(zb + 1 * 256 + kk);
        float4 z2 = *(const float4*)(zb + 2 * 256 + kk);
        float4 z3 = *(const float4*)(zb + 3 * 256 + kk);
        float4 z4 = *(const float4*)(zb + 4 * 256 + kk);
        float4 z5 = *(const float4*)(zb + 5 * 256 + kk);
        float4 z6 = *(const float4*)(zb + 6 * 256 + kk);
        float4 z7 = *(const float4*)(zb + 7 * 256 + kk);
        FMA4(a0, z0.x, w0) FMA4(a0, z0.y, w1) FMA4(a0, z0.z, w2) FMA4(a0, z0.w, w3)
        FMA4(a1, z1.x, w0) FMA4(a1, z1.y, w1) FMA4(a1, z1.z, w2) FMA4(a1, z1.w, w3)
        FMA4(a2, z2.x, w0) FMA4(a2, z2.y, w1) FMA4(a2, z2.z, w2) FMA4(a2, z2.w, w3)
        FMA4(a3, z3.x, w0) FMA4(a3, z3.y, w1) FMA4(a3, z3.z, w2) FMA4(a3, z3.w, w3)
        FMA4(a4, z4.x, w0) FMA4(a4, z4.y, w1) FMA4(a4, z4.z, w2) FMA4(a4, z4.w, w3)
        FMA4(a5, z5.x, w0) FMA4(a5, z5.y, w1) FMA4(a5, z5.z, w2) FMA4(a5, z5.w, w3)
        FMA4(a6, z6.x, w0) FMA4(a6, z6.y, w1) FMA4(a6, z6.z, w2) FMA4(a6, z6.w, w3)
        FMA4(a7, z7.x, w0) FMA4(a7, z7.y, w1) FMA4(a7, z7.z, w2) FMA4(a7, z7.w, w3)
    }
    float* pp = ps + kq * 2048 + 4 * ln;
    *(float4*)(pp + 0 * 256) = a0;
    *(float4*)(pp + 1 * 256) = a1;
    *(float4*)(pp + 2 * 256) = a2;
    *(float4*)(pp + 3 * 256) = a3;
    *(float4*)(pp + 4 * 256) = a4;
    *(float4*)(pp + 5 * 256) = a5;
    *(float4*)(pp + 6 * 256) = a6;
    *(float4*)(pp + 7 * 256) = a7;
}

__device__ __forceinline__ float4 combine8(const float* __restrict__ ps, int e)
{
    float4 a = *(const float4*)(ps + e);
    #pragma unroll
    for (int k = 1; k < 8; ++k) {
        float4 u = *(const float4*)(ps + k * 2048 + e);
        a.x += u.x; a.y += u.y; a.z += u.z; a.w += u.w;
    }
    return a;
}

// ---------------------------------------------------------------------------
// KA v3: patch embed + LN + NF + QKV. 256 blocks x 512 threads.
//  - Double-buffered partials psA/psB: combine of pass k overlaps GEMM of
//    pass k+1. In-register LN/NF (token = wave). [R8/R11 verified best]
// ---------------------------------------------------------------------------
__global__ __launch_bounds__(512, 2) void ka_patch_nf_qkv(
    const float* __restrict__ x,
    const float* __restrict__ Wp, const float* __restrict__ bp,
    const float* __restrict__ ln_g, const float* __restrict__ ln_b,
    const float* __restrict__ Wq, const float* __restrict__ bq,
    const float* __restrict__ Wk, const float* __restrict__ bk,
    const float* __restrict__ Wv, const float* __restrict__ bv,
    float* __restrict__ Qg, float* __restrict__ Kg, float* __restrict__ Vg)
{
    extern __shared__ float sm[];
    float* zr  = sm;           // [8][256] patch rows, then z rows
    float* psA = sm + 2048;    // [8][8][256] (64 KB)
    float* psB = sm + 18432;   // [8][8][256] (64 KB)

    const int tid = threadIdx.x;
    const int kq = tid >> 6, ln = tid & 63;
    const int lane = tid & 63;
    const int tok0 = blockIdx.x * 8;

    // ---- stage 8 patches as rows (float4/thread) ----
    {
        int e = tid * 4;
        int t = e >> 8, dd = e & 255;
        int tk = tok0 + t, b = tk >> 8, n = tk & 255;
        int ph = n >> 4, pw = n & 15, p = (dd >> 4) & 15, q = dd & 15;
        *(float4*)(zr + e) =
            *(const float4*)(x + b * 65536 + (ph * 16 + p) * 256 + pw * 16 + q);
    }
    __syncthreads();

    // ---- pass 0: z = patch @ Wp -> psA ----
    pass8x8(Wp, zr, psA, kq, ln);
    __syncthreads();

    // ---- combine + bias + in-register LN/NF (token = wave) ----
    {
        int e = tid * 4;                       // token tid>>6, dims 4*lane..+4
        float4 a = combine8(psA, e);
        float4 bb = *(const float4*)(bp + 4 * lane);
        a.x += bb.x; a.y += bb.y; a.z += bb.z; a.w += bb.w;

        float s  = a.x + a.y + a.z + a.w;
        float ss = a.x*a.x + a.y*a.y + a.z*a.z + a.w*a.w;
        #pragma unroll
        for (int o = 32; o; o >>= 1) { s += __shfl_xor(s, o); ss += __shfl_xor(ss, o); }
        float mu  = s * (1.f / 256.f);
        float var = ss * (1.f / 256.f) - mu * mu;
        float rs  = rsqrtf(var + EPSF);

        float4 g  = *(const float4*)(ln_g + 4 * lane);
        float4 b2 = *(const float4*)(ln_b + 4 * lane);
        float4 zn;
        zn.x = (a.x - mu) * rs * g.x + b2.x;
        zn.y = (a.y - mu) * rs * g.y + b2.y;
        zn.z = (a.z - mu) * rs * g.z + b2.z;
        zn.w = (a.w - mu) * rs * g.w + b2.w;

        float s2  = zn.x + zn.y + zn.z + zn.w;
        float ss2 = zn.x*zn.x + zn.y*zn.y + zn.z*zn.z + zn.w*zn.w;
        #pragma unroll
        for (int o = 32; o; o >>= 1) { s2 += __shfl_xor(s2, o); ss2 += __shfl_xor(ss2, o); }
        float mu2  = s2 * (1.f / 256.f);
        float var2 = ss2 * (1.f / 256.f) - mu2 * mu2;

        float as = fabsf(zn.x - mu2) + fabsf(zn.y - mu2)
                 + fabsf(zn.z - mu2) + fabsf(zn.w - mu2);
        #pragma unroll
        for (int o = 32; o; o >>= 1) as += __shfl_xor(as, o);
        float nf = as / (sqrtf(var2 + EPSF) + EPSF);
        float sc = 1.f + nf;
        zn.x *= sc; zn.y *= sc; zn.z *= sc; zn.w *= sc;
        *(float4*)(zr + e) = zn;
    }
    __syncthreads();

    // ---- QKV: double-buffered pass/combine pipeline ----
    int e = tid * 4, t = e >> 8, d0 = e & 255;
    int tk = tok0 + t, b = tk >> 8, n = tk & 255;
    int h = d0 >> 6, dh = d0 & 63;
    const long goff = ((long)(b * 4 + h) * 256 + n) * 64 + dh;

    pass8x8(Wq, zr, psB, kq, ln);
    __syncthreads();

    // phase: combine Q (psB) + pass K (psA)
    {
        float4 a = combine8(psB, e);
        float4 bb = *(const float4*)(bq + d0);
        a.x += bb.x; a.y += bb.y; a.z += bb.z; a.w += bb.w;
        *(float4*)(Qg + goff) = a;
    }
    pass8x8(Wk, zr, psA, kq, ln);
    __syncthreads();

    // phase: combine K (psA) + pass V (psB)
    {
        float4 a = combine8(psA, e);
        float4 bb = *(const float4*)(bk + d0);
        a.x += bb.x; a.y += bb.y; a.z += bb.z; a.w += bb.w;
        *(float4*)(Kg + goff) = a;
    }
    pass8x8(Wv, zr, psB, kq, ln);
    __syncthreads();

    // final: combine V (psB)
    {
        float4 a = combine8(psB, e);
        float4 bb = *(const float4*)(bv + d0);
        a.x += bb.x; a.y += bb.y; a.z += bb.z; a.w += bb.w;
        *(float4*)(Vg + goff) = a;
    }
}

// ---------------------------------------------------------------------------
// KB v4: AG-NFA attention — EXACT R7 form (verified -7.6 µs winner;
// R12's 1024-thread variant reverted: -5.3 µs regression).
// K and V staged in LDS (140 KB, free at 1 block/CU); Q + NF in registers.
// ---------------------------------------------------------------------------
__global__ __launch_bounds__(512, 2) void kb_attn(
    const float* __restrict__ Qg, const float* __restrict__ Kg,
    const float* __restrict__ Vg, float* __restrict__ Og)
{
    extern __shared__ float lds[];
    float* Kl = lds;                   // [256][KSTR]
    float* Vl = lds + 256 * KSTR;      // [256][KSTR]
    float* k2 = lds + 2 * 256 * KSTR;  // [256]
    float* Pl = Kl;                    // [32][PSTR] overlay on Kl after QK^T

    const int tid = threadIdx.x;
    const int xcd = blockIdx.x & 7, slot = blockIdx.x >> 3;
    const int bh = xcd * 4 + (slot >> 3);
    const int qt = slot & 7;

    const float* Qb = Qg + (bh * 256 + qt * 32) * 64;
    const float* Kb = Kg + bh * 16384;
    const float* Vb = Vg + bh * 16384;

    const int q = tid >> 4;   // 0..31: query row
    const int r = tid & 15;   // 0..15

    // ---- stage K and V -> LDS (fully coalesced) ----
    {
        const float4* Ks = (const float4*)Kb;
        const float4* Vs = (const float4*)Vb;
        #pragma unroll
        for (int i = 0; i < 8; ++i) {
            int flat = tid + 512 * i;            // f4 index, 4096 total
            int row = flat >> 4, c4 = flat & 15;
            *(float4*)(Kl + row * KSTR + c4 * 4) = Ks[flat];
            *(float4*)(Vl + row * KSTR + c4 * 4) = Vs[flat];
        }
    }
    __syncthreads();

    // ---- k2[m] = |K_m|^2 ----
    {
        int row = tid >> 1, half = tid & 1;
        const float* kp = Kl + row * KSTR + half * 32;
        float ssq = 0.f;
        #pragma unroll
        for (int c = 0; c < 8; ++c) {
            float4 kv = *(const float4*)(kp + 4 * c);
            ssq += kv.x*kv.x + kv.y*kv.y + kv.z*kv.z + kv.w*kv.w;
        }
        ssq += __shfl_xor(ssq, 1);
        if (half == 0) k2[row] = ssq;
    }

    // ---- Q row in registers + NF stats (thread-local) ----
    float4 Qr[16];
    {
        const float4* Qp = (const float4*)(Qb + q * 64);
        #pragma unroll
        for (int c = 0; c < 16; ++c) Qr[c] = Qp[c];
    }
    float fq, gq, iq;
    {
        float s = 0.f, ss = 0.f;
        #pragma unroll
        for (int c = 0; c < 16; ++c) {
            float4 v = Qr[c];
            s  += v.x + v.y + v.z + v.w;
            ss += v.x*v.x + v.y*v.y + v.z*v.z + v.w*v.w;
        }
        float mu = s * (1.f / 64.f);
        float as = 0.f;
        #pragma unroll
        for (int c = 0; c < 16; ++c) {
            float4 v = Qr[c];
            as += fabsf(v.x - mu) + fabsf(v.y - mu)
                + fabsf(v.z - mu) + fabsf(v.w - mu);
        }
        float var = ss * (1.f / 64.f) - mu * mu;
        float sg  = sqrtf(var + EPSF);
        float nf  = as / (sg + EPSF);
        float inv = 1.f / (__expf(-nf) + 1.f);
        fq = 0.125f + 2.f * inv;
        gq = ss * inv;
        iq = inv;
    }
    __syncthreads();   // k2 visible

    // ---- QK^T: scores for m = r + 16j ----
    float s_[16];
    #pragma unroll
    for (int j = 0; j < 16; ++j) {
        int m = r + 16 * j;
        const float* kp = Kl + m * KSTR;
        float acc = 0.f;
        #pragma unroll
        for (int c = 0; c < 16; ++c) {
            float4 kv = *(const float4*)(kp + 4 * c);
            acc += Qr[c].x*kv.x + Qr[c].y*kv.y + Qr[c].z*kv.z + Qr[c].w*kv.w;
        }
        s_[j] = acc * fq - gq - k2[m] * iq;
    }

    // ---- softmax over m ----
    float M = s_[0];
    #pragma unroll
    for (int j = 1; j < 16; ++j) M = fmaxf(M, s_[j]);
    #pragma unroll
    for (int o = 1; o < 16; o <<= 1) M = fmaxf(M, __shfl_xor(M, o));
    float L = 0.f;
    #pragma unroll
    for (int j = 0; j < 16; ++j) { s_[j] = __expf(s_[j] - M); L += s_[j]; }
    #pragma unroll
    for (int o = 1; o < 16; o <<= 1) L += __shfl_xor(L, o);
    float invL = 1.f / L;

    __syncthreads();   // done reading Kl/k2 -> overlay Pl (Vl untouched)
    #pragma unroll
    for (int j = 0; j < 16; ++j) Pl[q * PSTR + r + 16 * j] = s_[j] * invL;
    __syncthreads();

    // ---- PV: thread owns d = 4r..4r+4; V rows read from LDS ----
    float4 a0 = make_float4(0.f, 0.f, 0.f, 0.f);
    const float* pq = Pl + q * PSTR;
    const float* vp = Vl + 4 * r;
    #pragma unroll 8
    for (int m = 0; m < 256; ++m) {
        float pw = pq[m];
        float4 v = *(const float4*)(vp + m * KSTR);
        a0.x = fmaf(pw, v.x, a0.x); a0.y = fmaf(pw, v.y, a0.y);
        a0.z = fmaf(pw, v.z, a0.z); a0.w = fmaf(pw, v.w, a0.w);
    }
    {
        int b = bh >> 2, h = bh & 3;
        int n = qt * 32 + q;
        float* op = Og + (b * 256 + n) * 256 + h * 64 + 4 * r;
        *(float4*)op = a0;
    }
}

// ---------------------------------------------------------------------------
// KC v2: Y = attn_out @ Wo + bo, then LE-fusion. In-register ||Y|| (token =
// wave at the combine). [R8/R11 form, verified]
// ---------------------------------------------------------------------------
__global__ __launch_bounds__(512, 2) void kc_wo_le(
    const float* __restrict__ Og, const float* __restrict__ Wo,
    const float* __restrict__ bo, float* __restrict__ out)
{
    extern __shared__ float sm[];
    float* yr  = sm;           // [8][256]
    float* ps  = sm + 2048;    // [8][8][256] (64 KB)
    float* red = sm + 18432;   // [8]

    const int tid = threadIdx.x;
    const int kq = tid >> 6, ln = tid & 63;
    const int wave = tid >> 6, lane = tid & 63;
    const int tok0 = blockIdx.x * 8;

    *(float4*)(yr + tid * 4) = *(const float4*)(Og + tok0 * 256 + tid * 4);
    __syncthreads();

    pass8x8(Wo, yr, ps, kq, ln);
    __syncthreads();

    // combine + bias + in-register ||Y|| (token = wave), write yr row
    {
        int e = tid * 4;
        float4 a = combine8(ps, e);
        float4 bb = *(const float4*)(bo + 4 * lane);
        a.x += bb.x; a.y += bb.y; a.z += bb.z; a.w += bb.w;
        float ssq = a.x*a.x + a.y*a.y + a.z*a.z + a.w*a.w;
        #pragma unroll
        for (int o = 32; o; o >>= 1) ssq += __shfl_xor(ssq, o);
        if (lane == 0) red[wave] = sqrtf(ssq);
        *(float4*)(yr + e) = a;
    }
    __syncthreads();

    // LE-fusion
    {
        int g = tid >> 8, d = tid & 255;
        float e0 = red[4 * g], e1 = red[4 * g + 1], e2 = red[4 * g + 2], e3 = red[4 * g + 3];
        float m = fmaxf(fmaxf(e0, e1), fmaxf(e2, e3));
        float x0 = __expf(e0 - m), x1 = __expf(e1 - m), x2 = __expf(e2 - m), x3 = __expf(e3 - m);
        float inv = 1.f / (x0 + x1 + x2 + x3);
        float val = (x0 * yr[(4 * g) * 256 + d] + x1 * yr[(4 * g + 1) * 256 + d]
                   + x2 * yr[(4 * g + 2) * 256 + d] + x3 * yr[(4 * g + 3) * 256 + d]) * inv;
        out[(blockIdx.x * 2 + g) * 256 + d] = val;
    }
}

// ---------------------------------------------------------------------------
extern "C" void kernel_launch(void* const* d_in, const int* in_sizes, int n_in,
                              void* d_out, int out_size, void* d_ws, size_t ws_size,
                              hipStream_t stream) {
    const float* x    = (const float*)d_in[0];
    const float* Wp   = (const float*)d_in[1];
    const float* bp   = (const float*)d_in[2];
    const float* ln_g = (const float*)d_in[3];
    const float* ln_b = (const float*)d_in[4];
    const float* Wq   = (const float*)d_in[5];
    const float* bq   = (const float*)d_in[6];
    const float* Wk   = (const float*)d_in[7];
    const float* bk   = (const float*)d_in[8];
    const float* Wv   = (const float*)d_in[9];
    const float* bv   = (const float*)d_in[10];
    const float* Wo   = (const float*)d_in[11];
    const float* bo   = (const float*)d_in[12];
    float* out = (float*)d_out;

    float* ws = (float*)d_ws;
    float* Qg = ws;
    float* Kg = ws + 524288;
    float* Vg = ws + 524288 * 2;
    float* Og = ws + 524288 * 3;

    const int ka_lds = (2048 + 2 * 16384) * 4;          // 139264 B
    const int kb_lds = (2 * 256 * KSTR + 256) * 4;      // 140288 B
    const int kc_lds = (2048 + 16384 + 8) * 4;          // 73760 B
    (void)hipFuncSetAttribute((const void*)ka_patch_nf_qkv,
                              hipFuncAttributeMaxDynamicSharedMemorySize, ka_lds);
    (void)hipFuncSetAttribute((const void*)kb_attn,
                              hipFuncAttributeMaxDynamicSharedMemorySize, kb_lds);
    (void)hipFuncSetAttribute((const void*)kc_wo_le,
                              hipFuncAttributeMaxDynamicSharedMemorySize, kc_lds);

    ka_patch_nf_qkv<<<256, 512, ka_lds, stream>>>(x, Wp, bp, ln_g, ln_b,
                                                  Wq, bq, Wk, bk, Wv, bv, Qg, Kg, Vg);
    kb_attn<<<256, 512, kb_lds, stream>>>(Qg, Kg, Vg, Og);
    kc_wo_le<<<256, 512, kc_lds, stream>>>(Og, Wo, bo, out);
}